// Round 21
// baseline (351.965 us; speedup 1.0000x reference)
//
#include <hip/hip_runtime.h>
#include <hip/hip_bf16.h>

#define SDIM 128
#define NCOL 16384          // SDIM*SDIM
#define ROWS_TOTAL 4096
#define CHUNK 1024
#define RT_PC 64            // row-tiles per chunk
#define NCHUNK 4

using bf16x8 = __attribute__((ext_vector_type(8))) __bf16;
using su8    = __attribute__((ext_vector_type(8))) ushort;
using f32x4  = __attribute__((ext_vector_type(4))) float;

__device__ __forceinline__ ushort f2bf(float f) {
  __hip_bfloat16 h = __float2bfloat16(f);
  union { __hip_bfloat16 h; ushort u; } c; c.h = h;
  return c.u;
}

// ---- prep: L,R f32 -> bf16 in fragment-major layout ----
__global__ __launch_bounds__(256) void k_prep(const float* __restrict__ L,
                                              const float* __restrict__ R,
                                              ushort* __restrict__ Lt,
                                              ushort* __restrict__ Rt) {
  int id = blockIdx.x * 256 + threadIdx.x;
  const float* in = (id < 262144) ? L : R;
  ushort* outp    = (id < 262144) ? Lt : Rt;
  int t  = id & 262143;
  int t1 = t >> 11;
  int ks = (t >> 9) & 3;
  int tb = (t >> 6) & 7;
  int g  = (t >> 4) & 3;
  int tl = t & 15;
  const float* src = in + (size_t)(t1 * 128 + tb * 16 + tl) * 128 + ks * 32 + g * 8;
  float4 a = *reinterpret_cast<const float4*>(src);
  float4 b = *reinterpret_cast<const float4*>(src + 4);
  su8 o;
  o[0] = f2bf(a.x); o[1] = f2bf(a.y); o[2] = f2bf(a.z); o[3] = f2bf(a.w);
  o[4] = f2bf(b.x); o[5] = f2bf(b.y); o[6] = f2bf(b.z); o[7] = f2bf(b.w);
  *reinterpret_cast<su8*>(outp + (size_t)t * 8) = o;
}

// ======== stage1 body: 512 thr, block = 16 rows x 16 m (mg2 = sub&7) ========
__device__ __forceinline__ void s1_body(const float* __restrict__ x,
                                        const ushort* __restrict__ Lt,
                                        ushort* __restrict__ T3,
                                        int sub, ushort* sh, int tid) {
  int mg2 = sub & 7;
  int rt  = sub >> 3;
  int row0 = rt * 16;
  int m0 = mg2 * 16;

  // ---- stage x slice [16m][16r][128k] into LDS (f32->bf16), swizzled on r ----
  {
    int r = tid >> 5, kq = tid & 31;
    int k = kq << 2;
    const float4* p4 = reinterpret_cast<const float4*>(
        x + (size_t)(row0 + r) * NCOL + (size_t)k * SDIM + m0);
    float4 buf[16];
#pragma unroll
    for (int kk = 0; kk < 4; ++kk)
#pragma unroll
      for (int q = 0; q < 4; ++q)
        buf[kk * 4 + q] = p4[kk * 32 + q];
    ushort vv[4][16];
#pragma unroll
    for (int kk = 0; kk < 4; ++kk) {
#pragma unroll
      for (int q = 0; q < 4; ++q) {
        float4 a = buf[kk * 4 + q];
        vv[kk][q * 4 + 0] = f2bf(a.x); vv[kk][q * 4 + 1] = f2bf(a.y);
        vv[kk][q * 4 + 2] = f2bf(a.z); vv[kk][q * 4 + 3] = f2bf(a.w);
      }
    }
#pragma unroll
    for (int mloc = 0; mloc < 16; ++mloc) {
      int e = ((mloc * 16 + r) << 7) + k;
      int idx = e ^ ((r & 7) << 3);
      ushort4 w; w.x = vv[0][mloc]; w.y = vv[1][mloc];
                 w.z = vv[2][mloc]; w.w = vv[3][mloc];
      *reinterpret_cast<ushort4*>(&sh[idx]) = w;
    }
  }
  __syncthreads();

  int wave = tid >> 6, lane = tid & 63;
  int l15 = lane & 15, g = lane >> 4;
  int swz = (l15 & 7) << 3;
  int w4 = wave & 3, mgh = wave >> 2;
  int m0h = m0 + mgh * 8;
  const ushort* Lp = Lt + ((size_t)m0h * 32 + (size_t)w4 * 2) * 512 + (size_t)lane * 8;

  f32x4 st[2][8];
#pragma unroll
  for (int m = 0; m < 8; ++m) {
    int mloc = mgh * 8 + m;
    bf16x8 xf[4];
#pragma unroll
    for (int ks = 0; ks < 4; ++ks) {
      int e = ((mloc * 16 + l15) << 7) + ks * 32 + g * 8;
      xf[ks] = *reinterpret_cast<const bf16x8*>(&sh[e ^ swz]);
    }
    f32x4 a0 = {0.f, 0.f, 0.f, 0.f};
    f32x4 a1 = {0.f, 0.f, 0.f, 0.f};
#pragma unroll
    for (int ks = 0; ks < 4; ++ks) {
      bf16x8 l0 = *reinterpret_cast<const bf16x8*>(Lp + (size_t)((m * 4 + ks) * 8 + 0) * 512);
      bf16x8 l1 = *reinterpret_cast<const bf16x8*>(Lp + (size_t)((m * 4 + ks) * 8 + 1) * 512);
      a0 = __builtin_amdgcn_mfma_f32_16x16x32_bf16(xf[ks], l0, a0, 0, 0, 0);
      a1 = __builtin_amdgcn_mfma_f32_16x16x32_bf16(xf[ks], l1, a1, 0, 0, 0);
    }
    st[0][m] = a0;
    st[1][m] = a1;
  }

  int mg = mg2 * 2 + mgh;
  int ks1 = mg >> 2, g2 = mg & 3;
#pragma unroll
  for (int jt = 0; jt < 2; ++jt) {
    int j = w4 * 32 + jt * 16 + l15;
#pragma unroll
    for (int v = 0; v < 4; ++v) {
      int rr = g * 4 + v;
      su8 o;
      o[0] = f2bf(st[jt][0][v]); o[1] = f2bf(st[jt][1][v]);
      o[2] = f2bf(st[jt][2][v]); o[3] = f2bf(st[jt][3][v]);
      o[4] = f2bf(st[jt][4][v]); o[5] = f2bf(st[jt][5][v]);
      o[6] = f2bf(st[jt][6][v]); o[7] = f2bf(st[jt][7][v]);
      size_t a = (((size_t)(rt * 128 + j) * 4 + ks1) * 64 + g2 * 16 + rr) * 8;
      *reinterpret_cast<su8*>(T3 + a) = o;
    }
  }
}

// ======== stage2 body: 512 thr, jg = sub&7; T3 slice via global_load_lds ========
__device__ __forceinline__ void s2_body(const ushort* __restrict__ T3,
                                        const ushort* __restrict__ Rt,
                                        float* __restrict__ out,
                                        int sub, ushort* sh, int tid) {
  int jg = sub & 7;
  int rt = sub >> 3;
  int row0 = rt * 16;
  int j0 = jg * 16;

  int wave = tid >> 6, lane = tid & 63;
  int l15 = lane & 15, g = lane >> 4;
  int ibase = wave * 16;

  {
    const ushort* s = T3 + (size_t)(rt * 128 + j0) * 4 * 512;
#if __has_builtin(__builtin_amdgcn_global_load_lds)
#pragma unroll
    for (int q = 0; q < 8; ++q) {
      int off = q * 512 + tid;
      __builtin_amdgcn_global_load_lds(
          (const __attribute__((address_space(1))) unsigned int*)(s + (size_t)off * 8),
          (__attribute__((address_space(3))) unsigned int*)(sh + (size_t)off * 8),
          16, 0, 0);
    }
#else
    const su8* s8 = reinterpret_cast<const su8*>(s);
    su8* d8 = reinterpret_cast<su8*>(sh);
#pragma unroll
    for (int q = 0; q < 8; ++q)
      d8[q * 512 + tid] = s8[q * 512 + tid];
#endif
  }
  __syncthreads();

  f32x4 acc[16];
#pragma unroll
  for (int jj = 0; jj < 16; ++jj) acc[jj] = {0.f, 0.f, 0.f, 0.f};

  const ushort* Rp = Rt + ((size_t)j0 * 32 + wave) * 512 + (size_t)lane * 8;
  const ushort* tp = sh + (size_t)lane * 8;

#pragma unroll
  for (int jj = 0; jj < 16; ++jj) {
#pragma unroll
    for (int ks = 0; ks < 4; ++ks) {
      bf16x8 af = *reinterpret_cast<const bf16x8*>(tp + (size_t)(jj * 4 + ks) * 512);
      bf16x8 bf = *reinterpret_cast<const bf16x8*>(Rp + (size_t)(jj * 32 + ks * 8) * 512);
      acc[jj] = __builtin_amdgcn_mfma_f32_16x16x32_bf16(af, bf, acc[jj], 0, 0, 0);
    }
  }

#pragma unroll
  for (int v = 0; v < 4; ++v) {
    float* dst = out + (size_t)(row0 + g * 4 + v) * NCOL + (size_t)(ibase + l15) * SDIM + j0;
#pragma unroll
    for (int q = 0; q < 4; ++q) {
      float4 o; o.x = acc[q * 4 + 0][v]; o.y = acc[q * 4 + 1][v];
                o.z = acc[q * 4 + 2][v]; o.w = acc[q * 4 + 3][v];
      *reinterpret_cast<float4*>(dst + q * 4) = o;
    }
  }
}

// ---- single-role kernels (grid RT_PC*8 = 512) ----
__global__ __launch_bounds__(512, 2) void k_s1(const float* __restrict__ x,
                                               const ushort* __restrict__ Lt,
                                               ushort* __restrict__ T3) {
  __shared__ __align__(16) ushort sh[32768];
  s1_body(x, Lt, T3, blockIdx.x, sh, threadIdx.x);
}

__global__ __launch_bounds__(512, 2) void k_s2(const ushort* __restrict__ T3,
                                               const ushort* __restrict__ Rt,
                                               float* __restrict__ out) {
  __shared__ __align__(16) ushort sh[32768];
  s2_body(T3, Rt, out, blockIdx.x, sh, threadIdx.x);
}

// ---- merged kernel (grid 1024): role = bid&1 -> consecutive blocks alternate
// s2(chunk c) and s1(chunk c+1), so each CU's resident pair mixes an HBM-heavy
// s1 stage phase with an L2/LDS-heavy s2 compute phase.
__global__ __launch_bounds__(512, 2) void k_merge(const float* __restrict__ x_next,
                                                  const ushort* __restrict__ Lt,
                                                  const ushort* __restrict__ T3r,
                                                  ushort* __restrict__ T3w,
                                                  const ushort* __restrict__ Rt,
                                                  float* __restrict__ out_cur) {
  __shared__ __align__(16) ushort sh[32768];
  unsigned bid = blockIdx.x;
  int sub = bid >> 1;
  if (bid & 1) s1_body(x_next, Lt, T3w, sub, sh, threadIdx.x);
  else         s2_body(T3r, Rt, out_cur, sub, sh, threadIdx.x);
}

extern "C" void kernel_launch(void* const* d_in, const int* in_sizes, int n_in,
                              void* d_out, int out_size, void* d_ws, size_t ws_size,
                              hipStream_t stream) {
  const float* x = (const float*)d_in[0];
  const float* L = (const float*)d_in[1];
  const float* R = (const float*)d_in[2];
  float* out = (float*)d_out;

  ushort* Lt = (ushort*)d_ws;
  ushort* Rt = Lt + 2097152;
  ushort* T3a = Rt + 2097152;                   // 32 MB
  ushort* T3b = T3a + (size_t)CHUNK * NCOL;     // 32 MB
  const size_t need_db = (size_t)(8 + 64) * 1024 * 1024;

  k_prep<<<2048, 256, 0, stream>>>(L, R, Lt, Rt);

  if (ws_size >= need_db) {
    ushort* buf[2] = {T3a, T3b};
    k_s1<<<dim3(RT_PC * 8), 512, 0, stream>>>(x, Lt, buf[0]);
    for (int c = 0; c < NCHUNK - 1; ++c) {
      k_merge<<<dim3(RT_PC * 16), 512, 0, stream>>>(
          x + (size_t)(c + 1) * CHUNK * NCOL, Lt,
          buf[c & 1], buf[(c + 1) & 1], Rt,
          out + (size_t)c * CHUNK * NCOL);
    }
    k_s2<<<dim3(RT_PC * 8), 512, 0, stream>>>(buf[(NCHUNK - 1) & 1], Rt,
                                              out + (size_t)(NCHUNK - 1) * CHUNK * NCOL);
  } else {
    for (int c = 0; c < NCHUNK; ++c) {
      const float* xc = x + (size_t)c * CHUNK * NCOL;
      float* oc = out + (size_t)c * CHUNK * NCOL;
      k_s1<<<dim3(RT_PC * 8), 512, 0, stream>>>(xc, Lt, T3a);
      k_s2<<<dim3(RT_PC * 8), 512, 0, stream>>>(T3a, Rt, oc);
    }
  }
}

// Round 22
// 299.997 us; speedup vs baseline: 1.1732x; 1.1732x over previous
//
#include <hip/hip_runtime.h>
#include <hip/hip_bf16.h>

#define SDIM 128
#define NCOL 16384          // SDIM*SDIM
#define ROWS_TOTAL 4096
#define CHUNK 1024
#define RT_PC 64            // row-tiles per chunk
#define NCHUNK 4

using bf16x8 = __attribute__((ext_vector_type(8))) __bf16;
using su8    = __attribute__((ext_vector_type(8))) ushort;
using f32x4  = __attribute__((ext_vector_type(4))) float;

__device__ __forceinline__ ushort f2bf(float f) {
  __hip_bfloat16 h = __float2bfloat16(f);
  union { __hip_bfloat16 h; ushort u; } c; c.h = h;
  return c.u;
}

// ---- prep: L,R f32 -> bf16 in fragment-major layout ----
__global__ __launch_bounds__(256) void k_prep(const float* __restrict__ L,
                                              const float* __restrict__ R,
                                              ushort* __restrict__ Lt,
                                              ushort* __restrict__ Rt) {
  int id = blockIdx.x * 256 + threadIdx.x;
  const float* in = (id < 262144) ? L : R;
  ushort* outp    = (id < 262144) ? Lt : Rt;
  int t  = id & 262143;
  int t1 = t >> 11;
  int ks = (t >> 9) & 3;
  int tb = (t >> 6) & 7;
  int g  = (t >> 4) & 3;
  int tl = t & 15;
  const float* src = in + (size_t)(t1 * 128 + tb * 16 + tl) * 128 + ks * 32 + g * 8;
  float4 a = *reinterpret_cast<const float4*>(src);
  float4 b = *reinterpret_cast<const float4*>(src + 4);
  su8 o;
  o[0] = f2bf(a.x); o[1] = f2bf(a.y); o[2] = f2bf(a.z); o[3] = f2bf(a.w);
  o[4] = f2bf(b.x); o[5] = f2bf(b.y); o[6] = f2bf(b.z); o[7] = f2bf(b.w);
  *reinterpret_cast<su8*>(outp + (size_t)t * 8) = o;
}

// ======== stage1: 512 thr, block = 16 rows x 16 m (mg2 = bid&7 = XCD) ========
// Staging remap: 4 consecutive lanes (q) read the 4 quarters of ONE 64B line
// -> 16 line-lookups per wave load instr (was 64). Per-m 16-ushort runs are
// written as two b128s (swizzle XORs bits[5:3]; each 8-run stays 16B-aligned).
__global__ __launch_bounds__(512, 2) void k_s1(const float* __restrict__ x,
                                               const ushort* __restrict__ Lt,
                                               ushort* __restrict__ T3) {
  __shared__ __align__(16) ushort sh[32768];
  int tid = threadIdx.x;
  unsigned bid = blockIdx.x;
  int mg2 = bid & 7;
  int rt  = bid >> 3;              // chunk-local
  int row0 = rt * 16;
  int m0 = mg2 * 16;

  // ---- stage x slice [16m][16r][128k] into LDS (f32->bf16), swizzled on r ----
  {
    int r  = tid >> 5;             // 0..15
    int q  = tid & 3;              // 16B quarter: m sub-block q*4..q*4+4
    int k8 = (tid >> 2) & 7;       // 0..7 ; thread covers k = k8*16 .. k8*16+15
    const float* base = x + (size_t)(row0 + r) * NCOL + (size_t)(k8 * 16) * SDIM + m0 + q * 4;
    ushort vm[4][16];              // [mm][kk]
#pragma unroll
    for (int kk = 0; kk < 16; ++kk) {
      float4 a = *reinterpret_cast<const float4*>(base + (size_t)kk * SDIM);
      vm[0][kk] = f2bf(a.x); vm[1][kk] = f2bf(a.y);
      vm[2][kk] = f2bf(a.z); vm[3][kk] = f2bf(a.w);
    }
    int swz_w = (r & 7) << 3;
#pragma unroll
    for (int mm = 0; mm < 4; ++mm) {
      int mloc = q * 4 + mm;
      int ebase = ((mloc * 16 + r) << 7) + k8 * 16;
      su8 lo, hi;
#pragma unroll
      for (int e = 0; e < 8; ++e) { lo[e] = vm[mm][e]; hi[e] = vm[mm][8 + e]; }
      *reinterpret_cast<su8*>(&sh[ebase ^ swz_w]) = lo;
      *reinterpret_cast<su8*>(&sh[(ebase + 8) ^ swz_w]) = hi;
    }
  }
  __syncthreads();

  int wave = tid >> 6, lane = tid & 63;
  int l15 = lane & 15, g = lane >> 4;
  int swz = (l15 & 7) << 3;
  int w4 = wave & 3, mgh = wave >> 2;      // j-quadrant, m-half
  int m0h = m0 + mgh * 8;
  const ushort* Lp = Lt + ((size_t)m0h * 32 + (size_t)w4 * 2) * 512 + (size_t)lane * 8;

  f32x4 st[2][8];
#pragma unroll
  for (int m = 0; m < 8; ++m) {
    int mloc = mgh * 8 + m;
    bf16x8 xf[4];
#pragma unroll
    for (int ks = 0; ks < 4; ++ks) {
      int e = ((mloc * 16 + l15) << 7) + ks * 32 + g * 8;
      xf[ks] = *reinterpret_cast<const bf16x8*>(&sh[e ^ swz]);
    }
    f32x4 a0 = {0.f, 0.f, 0.f, 0.f};
    f32x4 a1 = {0.f, 0.f, 0.f, 0.f};
#pragma unroll
    for (int ks = 0; ks < 4; ++ks) {
      bf16x8 l0 = *reinterpret_cast<const bf16x8*>(Lp + (size_t)((m * 4 + ks) * 8 + 0) * 512);
      bf16x8 l1 = *reinterpret_cast<const bf16x8*>(Lp + (size_t)((m * 4 + ks) * 8 + 1) * 512);
      a0 = __builtin_amdgcn_mfma_f32_16x16x32_bf16(xf[ks], l0, a0, 0, 0, 0);
      a1 = __builtin_amdgcn_mfma_f32_16x16x32_bf16(xf[ks], l1, a1, 0, 0, 0);
    }
    st[0][m] = a0;
    st[1][m] = a1;
  }

  int mg = mg2 * 2 + mgh;
  int ks1 = mg >> 2, g2 = mg & 3;
#pragma unroll
  for (int jt = 0; jt < 2; ++jt) {
    int j = w4 * 32 + jt * 16 + l15;
#pragma unroll
    for (int v = 0; v < 4; ++v) {
      int rr = g * 4 + v;
      su8 o;
      o[0] = f2bf(st[jt][0][v]); o[1] = f2bf(st[jt][1][v]);
      o[2] = f2bf(st[jt][2][v]); o[3] = f2bf(st[jt][3][v]);
      o[4] = f2bf(st[jt][4][v]); o[5] = f2bf(st[jt][5][v]);
      o[6] = f2bf(st[jt][6][v]); o[7] = f2bf(st[jt][7][v]);
      size_t a = (((size_t)(rt * 128 + j) * 4 + ks1) * 64 + g2 * 16 + rr) * 8;
      *reinterpret_cast<su8*>(T3 + a) = o;
    }
  }
}

// ======== stage2: 512 thr, jg = bid&7 pinned to XCD; grid = RT_PC*8 ========
// T3 slice (64 KB contiguous) staged via async global_load_lds width=16.
__global__ __launch_bounds__(512, 2) void k_s2(const ushort* __restrict__ T3,
                                               const ushort* __restrict__ Rt,
                                               float* __restrict__ out) {
  __shared__ __align__(16) ushort sh[32768];
  int tid = threadIdx.x;
  unsigned bid = blockIdx.x;
  int jg = bid & 7;
  int rt = bid >> 3;
  int row0 = rt * 16;
  int j0 = jg * 16;

  int wave = tid >> 6, lane = tid & 63;
  int l15 = lane & 15, g = lane >> 4;
  int ibase = wave * 16;

  {
    const ushort* s = T3 + (size_t)(rt * 128 + j0) * 4 * 512;
#if __has_builtin(__builtin_amdgcn_global_load_lds)
#pragma unroll
    for (int q = 0; q < 8; ++q) {
      int off = q * 512 + tid;
      __builtin_amdgcn_global_load_lds(
          (const __attribute__((address_space(1))) unsigned int*)(s + (size_t)off * 8),
          (__attribute__((address_space(3))) unsigned int*)(sh + (size_t)off * 8),
          16, 0, 0);
    }
#else
    const su8* s8 = reinterpret_cast<const su8*>(s);
    su8* d8 = reinterpret_cast<su8*>(sh);
#pragma unroll
    for (int q = 0; q < 8; ++q)
      d8[q * 512 + tid] = s8[q * 512 + tid];
#endif
  }
  __syncthreads();

  f32x4 acc[16];
#pragma unroll
  for (int jj = 0; jj < 16; ++jj) acc[jj] = {0.f, 0.f, 0.f, 0.f};

  const ushort* Rp = Rt + ((size_t)j0 * 32 + wave) * 512 + (size_t)lane * 8;
  const ushort* tp = sh + (size_t)lane * 8;

#pragma unroll
  for (int jj = 0; jj < 16; ++jj) {
#pragma unroll
    for (int ks = 0; ks < 4; ++ks) {
      bf16x8 af = *reinterpret_cast<const bf16x8*>(tp + (size_t)(jj * 4 + ks) * 512);
      bf16x8 bf = *reinterpret_cast<const bf16x8*>(Rp + (size_t)(jj * 32 + ks * 8) * 512);
      acc[jj] = __builtin_amdgcn_mfma_f32_16x16x32_bf16(af, bf, acc[jj], 0, 0, 0);
    }
  }

#pragma unroll
  for (int v = 0; v < 4; ++v) {
    float* dst = out + (size_t)(row0 + g * 4 + v) * NCOL + (size_t)(ibase + l15) * SDIM + j0;
#pragma unroll
    for (int q = 0; q < 4; ++q) {
      float4 o; o.x = acc[q * 4 + 0][v]; o.y = acc[q * 4 + 1][v];
                o.z = acc[q * 4 + 2][v]; o.w = acc[q * 4 + 3][v];
      *reinterpret_cast<float4*>(dst + q * 4) = o;
    }
  }
}

extern "C" void kernel_launch(void* const* d_in, const int* in_sizes, int n_in,
                              void* d_out, int out_size, void* d_ws, size_t ws_size,
                              hipStream_t stream) {
  const float* x = (const float*)d_in[0];
  const float* L = (const float*)d_in[1];
  const float* R = (const float*)d_in[2];
  float* out = (float*)d_out;

  ushort* Lt = (ushort*)d_ws;
  ushort* Rt = Lt + 2097152;
  ushort* T3 = Rt + 2097152;      // 32 MB chunk buffer (L3-resident round-trip)

  k_prep<<<2048, 256, 0, stream>>>(L, R, Lt, Rt);

  for (int c = 0; c < NCHUNK; ++c) {
    const float* xc = x + (size_t)c * CHUNK * NCOL;
    float* oc = out + (size_t)c * CHUNK * NCOL;
    k_s1<<<dim3(RT_PC * 8), 512, 0, stream>>>(xc, Lt, T3);
    k_s2<<<dim3(RT_PC * 8), 512, 0, stream>>>(T3, Rt, oc);
  }
}